// Round 9
// baseline (16.090 us; speedup 1.0000x reference)
//
#include <hip/hip_runtime.h>

#define B_    32
#define T_    256
#define D_    64
#define NSEG_ 32
#define OUTD_ 2080          // 64 + 2016
#define NTRI  2016
#define NCHUNK 520          // OUTD_/4

typedef float v4f __attribute__((ext_vector_type(4)));

// starts[k] = int(round(1 + k*255/32)) - 1, Python banker's rounding.
// Exact in double; rint() (RNE) is bit-identical to numpy.
__device__ __forceinline__ int boundary(int k) {
    double v = 1.0 + (double)k * (255.0 / 32.0);
    return (int)rint(v) - 1;
}
// triu(k=1) elements before row d: d*(127-d)/2
__device__ __forceinline__ int cum(int d) { return (d * (127 - d)) >> 1; }

__global__ __launch_bounds__(256)
void logsig_kernel(const float* __restrict__ inp, float* __restrict__ out) {
    const int s = blockIdx.x;   // segment
    const int b = blockIdx.y;   // batch
    const int t0 = boundary(s);
    const int t1 = boundary(s + 1);
    const int n  = t1 - t0;     // 7 or 8; t0+8 <= 255 for all s

    __shared__ float xs[9][D_];     // 2304 B
    __shared__ float tri[NTRI];     // 8064 B

    // phase 1: stage 9 rows of input (always safe: t0+8 <= 255)
    {
        const v4f* src4 = (const v4f*)(inp + ((size_t)b * T_ + t0) * D_);
        const int i = threadIdx.x;
        if (i < 144) ((v4f*)&xs[0][0])[i] = src4[i];
    }
    __syncthreads();

    // phase 2: 136 upper-tri 4x4 tiles, one per thread
    const int tau = threadIdx.x;
    if (tau < 136) {
        // decode tau -> (ti, tj): row ti has 16-ti tiles (tj = ti..15)
        int r = 0, F = 0;
        while (F + (16 - r) <= tau) { F += 16 - r; ++r; }
        const int ti = r, tj = r + (tau - F);
        const int d0 = ti * 4, e0 = tj * 4;

        v4f xd[9], xe[9];
        #pragma unroll
        for (int k = 0; k < 9; ++k) {
            xd[k] = *(const v4f*)&xs[k][d0];   // ds_read_b128
            xe[k] = *(const v4f*)&xs[k][e0];   // ds_read_b128
        }

        float acc[4][4];
        #pragma unroll
        for (int a = 0; a < 4; ++a)
            #pragma unroll
            for (int bb = 0; bb < 4; ++bb) acc[a][bb] = 0.f;

        // A[d,e] = 0.5*( sum_{k<n} (xd[k]*xe[k+1] - xe[k]*xd[k+1])
        //               - (xd[0]*xe[n] - xe[0]*xd[n]) )
        #pragma unroll
        for (int k = 0; k < 8; ++k) {
            if (k < n) {
                #pragma unroll
                for (int a = 0; a < 4; ++a) {
                    #pragma unroll
                    for (int bb = 0; bb < 4; ++bb) {
                        acc[a][bb] = fmaf(xd[k][a],    xe[k + 1][bb], acc[a][bb]);
                        acc[a][bb] = fmaf(-xd[k + 1][a], xe[k][bb],   acc[a][bb]);
                    }
                }
            }
        }
        #pragma unroll
        for (int a = 0; a < 4; ++a) {
            #pragma unroll
            for (int bb = 0; bb < 4; ++bb) {
                acc[a][bb] = fmaf(-xd[0][a], xe[n][bb], acc[a][bb]);
                acc[a][bb] = fmaf( xd[n][a], xe[0][bb], acc[a][bb]);
            }
        }

        // scatter into LDS triangle buffer
        #pragma unroll
        for (int a = 0; a < 4; ++a) {
            const int d = d0 + a;
            const int base = cum(d) - d - 1;   // + e gives flat index
            #pragma unroll
            for (int bb = 0; bb < 4; ++bb) {
                const int e = e0 + bb;
                if (e > d) tri[base + e] = 0.5f * acc[a][bb];
            }
        }
    }
    __syncthreads();

    // phase 3: stream out, lane-consecutive float4 stores (L2-merged full lines)
    v4f* o4 = (v4f*)(out + ((size_t)b * NSEG_ + s) * OUTD_);
    for (int c = threadIdx.x; c < NCHUNK; c += 256) {
        v4f r;
        if (c < 16) {
            const v4f xa = *(const v4f*)&xs[0][c * 4];
            const v4f xb = *(const v4f*)&xs[n][c * 4];
            r = xb - xa;
        } else {
            r = *(const v4f*)&tri[4 * c - 64];   // 16B-aligned LDS read
        }
        o4[c] = r;
    }
}

extern "C" void kernel_launch(void* const* d_in, const int* in_sizes, int n_in,
                              void* d_out, int out_size, void* d_ws, size_t ws_size,
                              hipStream_t stream) {
    const float* inp = (const float*)d_in[0];
    float* out = (float*)d_out;
    dim3 grid(NSEG_, B_);
    dim3 block(256);
    hipLaunchKernelGGL(logsig_kernel, grid, block, 0, stream, inp, out);
}